// Round 1
// baseline (2138.186 us; speedup 1.0000x reference)
//
#include <hip/hip_runtime.h>

#define HDIM 128
#define SEQ  14
#define G4   512   // 4*H
#define TLEN 8

__device__ __forceinline__ float sigmoidf_(float x) {
    return 1.0f / (1.0f + __expf(-x));
}

// One block per batch element. 512 threads: thread j owns gate-column j of the
// recurrent weight matrix (128 fp32 VGPRs). h is broadcast from LDS each step.
__global__ __launch_bounds__(512, 2) void seq2seq_kernel(
    const float* __restrict__ inputs,   // [B, 14, 1]
    const float* __restrict__ Wih_e,    // [1, 512]
    const float* __restrict__ Whh_e,    // [128, 512]
    const float* __restrict__ b_e,      // [512]
    const float* __restrict__ Wih_d,
    const float* __restrict__ Whh_d,
    const float* __restrict__ b_d,
    const float* __restrict__ We,       // [128, 128]
    const float* __restrict__ Wd,       // [128, 128]
    const float* __restrict__ Wv,       // [128, 1]
    const float* __restrict__ Wf,       // [128, 1]
    const float* __restrict__ bfp,      // [1]
    float* __restrict__ out,            // [B*8] outputs then [B*14] total_attn
    int B)
{
    const int tid = threadIdx.x;
    const int b   = blockIdx.x;

    __shared__ __align__(16) float sh_h[HDIM];
    __shared__ __align__(16) float sh_g[G4];
    __shared__ __align__(16) float sh_enc[SEQ][HDIM];
    __shared__ __align__(16) float sh_encWe[SEQ][HDIM];
    __shared__ __align__(16) float sh_hWd[HDIM];
    __shared__ __align__(16) float sh_part[4][HDIM];
    __shared__ __align__(16) float sh_ctx[HDIM];
    __shared__ float sh_attn[SEQ];
    __shared__ float sh_attnsum[SEQ];
    __shared__ float sh_score[SEQ];
    __shared__ float sh_x;

    float w[HDIM];  // recurrent weight column `tid` (register-resident)

    // ---------------- Phase 1: encoder ----------------
    #pragma unroll
    for (int k = 0; k < HDIM; ++k) w[k] = Whh_e[k * G4 + tid];
    float wih = Wih_e[tid];
    float bb  = b_e[tid];

    if (tid < HDIM) sh_h[tid] = 0.0f;
    if (tid < SEQ)  sh_attnsum[tid] = 0.0f;
    float c = 0.0f;  // cell state, valid for tid < 128
    __syncthreads();

    const float* inp_b = inputs + b * SEQ;

    for (int t = 0; t < SEQ; ++t) {
        float x = inp_b[t];
        float acc = fmaf(x, wih, bb);
        #pragma unroll
        for (int k = 0; k < HDIM; k += 4) {
            float4 hv = *(const float4*)(sh_h + k);
            acc = fmaf(hv.x, w[k],     acc);
            acc = fmaf(hv.y, w[k + 1], acc);
            acc = fmaf(hv.z, w[k + 2], acc);
            acc = fmaf(hv.w, w[k + 3], acc);
        }
        sh_g[tid] = acc;
        __syncthreads();
        if (tid < HDIM) {
            float ig = sigmoidf_(sh_g[tid]);
            float fg = sigmoidf_(sh_g[tid + HDIM]);
            float gg = tanhf(sh_g[tid + 2 * HDIM]);
            float og = sigmoidf_(sh_g[tid + 3 * HDIM]);
            c = fmaf(fg, c, ig * gg);
            float hn = og * tanhf(c);
            sh_h[tid] = hn;
            sh_enc[t][tid] = hn;
        }
        __syncthreads();
    }

    // Precompute enc_out @ We once (reused by all 8 decoder steps).
    for (int idx = tid; idx < SEQ * HDIM; idx += 512) {
        int t = idx >> 7, j = idx & 127;
        float a = 0.0f;
        for (int k = 0; k < HDIM; ++k)
            a = fmaf(sh_enc[t][k], We[k * HDIM + j], a);
        sh_encWe[t][j] = a;
    }

    // ---------------- Phase 2: decoder ----------------
    #pragma unroll
    for (int k = 0; k < HDIM; ++k) w[k] = Whh_d[k * G4 + tid];
    wih = Wih_d[tid];
    bb  = b_d[tid];

    if (tid == 0) sh_x = inp_b[SEQ - 1];
    __syncthreads();  // encWe + x visible

    for (int d = 0; d < TLEN; ++d) {
        // --- attention: hWd[j] = sum_k h[k] * Wd[k][j], 4-way k-split ---
        {
            int j = tid & 127, p = tid >> 7;
            float a = 0.0f;
            const float* wd = Wd + (p * 32) * HDIM + j;
            #pragma unroll
            for (int k = 0; k < 32; ++k)
                a = fmaf(sh_h[p * 32 + k], wd[k * HDIM], a);
            sh_part[p][j] = a;
        }
        __syncthreads();
        if (tid < HDIM)
            sh_hWd[tid] = sh_part[0][tid] + sh_part[1][tid] + sh_part[2][tid] + sh_part[3][tid];
        __syncthreads();

        // --- scores: e[t] = sum_j tanh(encWe[t][j] + hWd[j]) * Wv[j] ---
        if (tid < SEQ * 32) {
            int t = tid >> 5, l = tid & 31;
            float s = 0.0f;
            #pragma unroll
            for (int j0 = 0; j0 < HDIM; j0 += 32)
                s = fmaf(tanhf(sh_encWe[t][j0 + l] + sh_hWd[j0 + l]), Wv[j0 + l], s);
            s += __shfl_down(s, 16, 32);
            s += __shfl_down(s, 8, 32);
            s += __shfl_down(s, 4, 32);
            s += __shfl_down(s, 2, 32);
            s += __shfl_down(s, 1, 32);
            if (l == 0) sh_score[t] = s;
        }
        __syncthreads();

        // --- softmax over 14 (serial, tiny) ---
        if (tid == 0) {
            float m = sh_score[0];
            for (int t = 1; t < SEQ; ++t) m = fmaxf(m, sh_score[t]);
            float ssum = 0.0f;
            for (int t = 0; t < SEQ; ++t) {
                float ev = __expf(sh_score[t] - m);
                sh_attn[t] = ev;
                ssum += ev;
            }
            float inv = 1.0f / ssum;
            for (int t = 0; t < SEQ; ++t) {
                float a = sh_attn[t] * inv;
                sh_attn[t] = a;
                sh_attnsum[t] += a;
            }
        }
        __syncthreads();

        // --- context[k] = sum_t attn[t] * enc_out[t][k] ---
        if (tid < HDIM) {
            float a = 0.0f;
            #pragma unroll
            for (int t = 0; t < SEQ; ++t)
                a = fmaf(sh_attn[t], sh_enc[t][tid], a);
            sh_ctx[tid] = a;
        }
        __syncthreads();

        // --- decoder LSTM: 129 scalar-input steps ---
        for (int s = 0; s < HDIM + 1; ++s) {
            float x = (s < HDIM) ? sh_ctx[s] : sh_x;
            float acc = fmaf(x, wih, bb);
            #pragma unroll
            for (int k = 0; k < HDIM; k += 4) {
                float4 hv = *(const float4*)(sh_h + k);
                acc = fmaf(hv.x, w[k],     acc);
                acc = fmaf(hv.y, w[k + 1], acc);
                acc = fmaf(hv.z, w[k + 2], acc);
                acc = fmaf(hv.w, w[k + 3], acc);
            }
            sh_g[tid] = acc;
            __syncthreads();
            if (tid < HDIM) {
                float ig = sigmoidf_(sh_g[tid]);
                float fg = sigmoidf_(sh_g[tid + HDIM]);
                float gg = tanhf(sh_g[tid + 2 * HDIM]);
                float og = sigmoidf_(sh_g[tid + 3 * HDIM]);
                c = fmaf(fg, c, ig * gg);
                float hn = og * tanhf(c);
                sh_h[tid] = hn;
            }
            __syncthreads();
        }

        // --- out = h @ Wf + bf (scalar); also becomes next x ---
        if (tid < 64) {
            float s = sh_h[tid] * Wf[tid] + sh_h[tid + 64] * Wf[tid + 64];
            s += __shfl_down(s, 32);
            s += __shfl_down(s, 16);
            s += __shfl_down(s, 8);
            s += __shfl_down(s, 4);
            s += __shfl_down(s, 2);
            s += __shfl_down(s, 1);
            if (tid == 0) {
                float o = s + bfp[0];
                out[b * TLEN + d] = o;
                sh_x = o;
            }
        }
        __syncthreads();
    }

    // total_attn [B, 14, 1]
    if (tid < SEQ) out[B * TLEN + b * SEQ + tid] = sh_attnsum[tid];
}

extern "C" void kernel_launch(void* const* d_in, const int* in_sizes, int n_in,
                              void* d_out, int out_size, void* d_ws, size_t ws_size,
                              hipStream_t stream) {
    const float* inputs = (const float*)d_in[0];
    // d_in[1] = target_len (== 8, hardcoded as TLEN)
    const float* Wih_e = (const float*)d_in[2];
    const float* Whh_e = (const float*)d_in[3];
    const float* b_e   = (const float*)d_in[4];
    const float* Wih_d = (const float*)d_in[5];
    const float* Whh_d = (const float*)d_in[6];
    const float* b_d   = (const float*)d_in[7];
    const float* We    = (const float*)d_in[8];
    const float* Wd    = (const float*)d_in[9];
    const float* Wv    = (const float*)d_in[10];
    const float* Wf    = (const float*)d_in[11];
    const float* bfp   = (const float*)d_in[12];
    float* out = (float*)d_out;

    const int B = in_sizes[0] / SEQ;  // 512

    seq2seq_kernel<<<dim3(B), dim3(512), 0, stream>>>(
        inputs, Wih_e, Whh_e, b_e, Wih_d, Whh_d, b_d, We, Wd, Wv, Wf, bfp, out, B);
}

// Round 2
// 1518.672 us; speedup vs baseline: 1.4079x; 1.4079x over previous
//
#include <hip/hip_runtime.h>

#define HDIM 128
#define SEQ  14
#define G4   512   // 4*H
#define TLEN 8

__device__ __forceinline__ float frcp_(float x) { return __builtin_amdgcn_rcpf(x); }
__device__ __forceinline__ float fsig_(float x) { return frcp_(1.0f + __expf(-x)); }
__device__ __forceinline__ float ftanh_(float x) {
    // tanh(x) = 1 - 2/(e^{2x}+1); saturates correctly for |x| large.
    return 1.0f - 2.0f * frcp_(__expf(2.0f * x) + 1.0f);
}

// One block per 2 batch elements. 512 threads: thread j owns gate-column j of
// the recurrent weight matrix (shared by both elements). h broadcast from LDS.
__global__ __launch_bounds__(512, 2) void seq2seq_kernel(
    const float* __restrict__ inputs,   // [B, 14, 1]
    const float* __restrict__ Wih_e,    // [1, 512]
    const float* __restrict__ Whh_e,    // [128, 512]
    const float* __restrict__ b_e,      // [512]
    const float* __restrict__ Wih_d,
    const float* __restrict__ Whh_d,
    const float* __restrict__ b_d,
    const float* __restrict__ We,       // [128, 128]
    const float* __restrict__ Wd,       // [128, 128]
    const float* __restrict__ Wv,       // [128, 1]
    const float* __restrict__ Wf,       // [128, 1]
    const float* __restrict__ bfp,      // [1]
    float* __restrict__ out,            // [B*8] outputs then [B*14] total_attn
    int B)
{
    const int tid = threadIdx.x;
    const int b0  = blockIdx.x * 2;      // first of the two batch elements

    __shared__ __align__(16) float sh_h[2][HDIM];
    __shared__ __align__(16) float sh_g[2][G4];
    __shared__ __align__(16) float sh_enc[2][SEQ][HDIM];
    __shared__ __align__(16) float sh_encWe[2][SEQ][HDIM];
    __shared__ __align__(16) float sh_hWd[2][HDIM];
    __shared__ __align__(16) float sh_part[2][2][HDIM];
    __shared__ __align__(16) float sh_ctx[2][HDIM];
    __shared__ float sh_attn[2][SEQ];
    __shared__ float sh_attnsum[2][SEQ];
    __shared__ float sh_score[2][SEQ];
    __shared__ float sh_x[2];

    float w[HDIM];  // recurrent weight column `tid`, shared by both elements

    // ---------------- Phase 1: encoder ----------------
    #pragma unroll
    for (int k = 0; k < HDIM; ++k) w[k] = Whh_e[k * G4 + tid];
    float wih = Wih_e[tid];
    float bb  = b_e[tid];

    if (tid < 2 * HDIM) sh_h[tid >> 7][tid & 127] = 0.0f;
    if (tid < 2 * SEQ)  sh_attnsum[tid / SEQ][tid % SEQ] = 0.0f;
    float c = 0.0f;  // cell state for (e = tid>>7, j = tid&127), valid tid < 256
    __syncthreads();

    const float* inp0 = inputs + b0 * SEQ;
    const float* inp1 = inputs + (b0 + 1) * SEQ;

    for (int t = 0; t < SEQ; ++t) {
        float a0 = fmaf(inp0[t], wih, bb), a0b = 0.0f;
        float a1 = fmaf(inp1[t], wih, bb), a1b = 0.0f;
        #pragma unroll
        for (int k = 0; k < HDIM; k += 8) {
            float4 p0 = *(const float4*)(&sh_h[0][k]);
            float4 q0 = *(const float4*)(&sh_h[0][k + 4]);
            float4 p1 = *(const float4*)(&sh_h[1][k]);
            float4 q1 = *(const float4*)(&sh_h[1][k + 4]);
            a0  = fmaf(p0.x, w[k],     a0);  a0  = fmaf(p0.y, w[k + 1], a0);
            a0  = fmaf(p0.z, w[k + 2], a0);  a0  = fmaf(p0.w, w[k + 3], a0);
            a0b = fmaf(q0.x, w[k + 4], a0b); a0b = fmaf(q0.y, w[k + 5], a0b);
            a0b = fmaf(q0.z, w[k + 6], a0b); a0b = fmaf(q0.w, w[k + 7], a0b);
            a1  = fmaf(p1.x, w[k],     a1);  a1  = fmaf(p1.y, w[k + 1], a1);
            a1  = fmaf(p1.z, w[k + 2], a1);  a1  = fmaf(p1.w, w[k + 3], a1);
            a1b = fmaf(q1.x, w[k + 4], a1b); a1b = fmaf(q1.y, w[k + 5], a1b);
            a1b = fmaf(q1.z, w[k + 6], a1b); a1b = fmaf(q1.w, w[k + 7], a1b);
        }
        sh_g[0][tid] = a0 + a0b;
        sh_g[1][tid] = a1 + a1b;
        __syncthreads();
        if (tid < 256) {
            int e = tid >> 7, j = tid & 127;
            float ig = fsig_(sh_g[e][j]);
            float fg = fsig_(sh_g[e][j + HDIM]);
            float gg = ftanh_(sh_g[e][j + 2 * HDIM]);
            float og = fsig_(sh_g[e][j + 3 * HDIM]);
            c = fmaf(fg, c, ig * gg);
            float hn = og * ftanh_(c);
            sh_h[e][j] = hn;
            sh_enc[e][t][j] = hn;
        }
        __syncthreads();
    }

    // Precompute enc_out @ We once (reused by all 8 decoder steps).
    for (int idx = tid; idx < 2 * SEQ * HDIM; idx += 512) {
        int e = idx / (SEQ * HDIM), r = idx % (SEQ * HDIM);
        int t = r >> 7, j = r & 127;
        float a = 0.0f;
        for (int k = 0; k < HDIM; ++k)
            a = fmaf(sh_enc[e][t][k], We[k * HDIM + j], a);
        sh_encWe[e][t][j] = a;
    }

    // ---------------- Phase 2: decoder ----------------
    #pragma unroll
    for (int k = 0; k < HDIM; ++k) w[k] = Whh_d[k * G4 + tid];
    wih = Wih_d[tid];
    bb  = b_d[tid];

    if (tid < 2) sh_x[tid] = inputs[(b0 + tid) * SEQ + (SEQ - 1)];
    __syncthreads();  // encWe + x visible

    for (int d = 0; d < TLEN; ++d) {
        // --- attention: hWd[e][j] = sum_k h[e][k] * Wd[k][j], 2-way k-split ---
        {
            int e = tid >> 8, p = (tid >> 7) & 1, j = tid & 127;
            float a = 0.0f;
            const float* wd = Wd + (p * 64) * HDIM + j;
            #pragma unroll
            for (int k = 0; k < 64; ++k)
                a = fmaf(sh_h[e][p * 64 + k], wd[k * HDIM], a);
            sh_part[e][p][j] = a;
        }
        __syncthreads();
        if (tid < 256) {
            int e = tid >> 7, j = tid & 127;
            sh_hWd[e][j] = sh_part[e][0][j] + sh_part[e][1][j];
        }
        __syncthreads();

        // --- scores: e[t] = sum_j tanh(encWe[t][j] + hWd[j]) * Wv[j] ---
        if (tid < 2 * SEQ * 16) {
            int e = tid / (SEQ * 16), r = tid % (SEQ * 16);
            int t = r >> 4, l = r & 15;
            float s = 0.0f;
            #pragma unroll
            for (int j0 = 0; j0 < HDIM; j0 += 16)
                s = fmaf(ftanh_(sh_encWe[e][t][j0 + l] + sh_hWd[e][j0 + l]), Wv[j0 + l], s);
            s += __shfl_down(s, 8, 16);
            s += __shfl_down(s, 4, 16);
            s += __shfl_down(s, 2, 16);
            s += __shfl_down(s, 1, 16);
            if (l == 0) sh_score[e][t] = s;
        }
        __syncthreads();

        // --- softmax over 14 (serial per element, tiny; e0 on wave0, e1 on wave1) ---
        if ((tid & 63) == 0 && tid < 128) {
            int e = tid >> 6;
            float m = sh_score[e][0];
            for (int t = 1; t < SEQ; ++t) m = fmaxf(m, sh_score[e][t]);
            float ssum = 0.0f;
            for (int t = 0; t < SEQ; ++t) {
                float ev = __expf(sh_score[e][t] - m);
                sh_attn[e][t] = ev;
                ssum += ev;
            }
            float inv = frcp_(ssum);
            for (int t = 0; t < SEQ; ++t) {
                float a = sh_attn[e][t] * inv;
                sh_attn[e][t] = a;
                sh_attnsum[e][t] += a;
            }
        }
        __syncthreads();

        // --- context[e][k] = sum_t attn[e][t] * enc_out[e][t][k] ---
        if (tid < 256) {
            int e = tid >> 7, j = tid & 127;
            float a = 0.0f;
            #pragma unroll
            for (int t = 0; t < SEQ; ++t)
                a = fmaf(sh_attn[e][t], sh_enc[e][t][j], a);
            sh_ctx[e][j] = a;
        }
        __syncthreads();

        // --- decoder LSTM: 129 scalar-input steps ---
        for (int s = 0; s < HDIM + 1; ++s) {
            float x0 = (s < HDIM) ? sh_ctx[0][s] : sh_x[0];
            float x1 = (s < HDIM) ? sh_ctx[1][s] : sh_x[1];
            float a0 = fmaf(x0, wih, bb), a0b = 0.0f;
            float a1 = fmaf(x1, wih, bb), a1b = 0.0f;
            #pragma unroll
            for (int k = 0; k < HDIM; k += 8) {
                float4 p0 = *(const float4*)(&sh_h[0][k]);
                float4 q0 = *(const float4*)(&sh_h[0][k + 4]);
                float4 p1 = *(const float4*)(&sh_h[1][k]);
                float4 q1 = *(const float4*)(&sh_h[1][k + 4]);
                a0  = fmaf(p0.x, w[k],     a0);  a0  = fmaf(p0.y, w[k + 1], a0);
                a0  = fmaf(p0.z, w[k + 2], a0);  a0  = fmaf(p0.w, w[k + 3], a0);
                a0b = fmaf(q0.x, w[k + 4], a0b); a0b = fmaf(q0.y, w[k + 5], a0b);
                a0b = fmaf(q0.z, w[k + 6], a0b); a0b = fmaf(q0.w, w[k + 7], a0b);
                a1  = fmaf(p1.x, w[k],     a1);  a1  = fmaf(p1.y, w[k + 1], a1);
                a1  = fmaf(p1.z, w[k + 2], a1);  a1  = fmaf(p1.w, w[k + 3], a1);
                a1b = fmaf(q1.x, w[k + 4], a1b); a1b = fmaf(q1.y, w[k + 5], a1b);
                a1b = fmaf(q1.z, w[k + 6], a1b); a1b = fmaf(q1.w, w[k + 7], a1b);
            }
            sh_g[0][tid] = a0 + a0b;
            sh_g[1][tid] = a1 + a1b;
            __syncthreads();
            if (tid < 256) {
                int e = tid >> 7, j = tid & 127;
                float ig = fsig_(sh_g[e][j]);
                float fg = fsig_(sh_g[e][j + HDIM]);
                float gg = ftanh_(sh_g[e][j + 2 * HDIM]);
                float og = fsig_(sh_g[e][j + 3 * HDIM]);
                c = fmaf(fg, c, ig * gg);
                sh_h[e][j] = og * ftanh_(c);
            }
            __syncthreads();
        }

        // --- out = h @ Wf + bf (scalar per elem); also becomes next x ---
        if (tid < 128) {
            int e = tid >> 6, l = tid & 63;
            float s = sh_h[e][l] * Wf[l] + sh_h[e][l + 64] * Wf[l + 64];
            s += __shfl_down(s, 32);
            s += __shfl_down(s, 16);
            s += __shfl_down(s, 8);
            s += __shfl_down(s, 4);
            s += __shfl_down(s, 2);
            s += __shfl_down(s, 1);
            if (l == 0) {
                float o = s + bfp[0];
                out[(b0 + e) * TLEN + d] = o;
                sh_x[e] = o;
            }
        }
        __syncthreads();
    }

    // total_attn [B, 14, 1]
    if (tid < 2 * SEQ) {
        int e = tid / SEQ, t = tid % SEQ;
        out[B * TLEN + (b0 + e) * SEQ + t] = sh_attnsum[e][t];
    }
}

extern "C" void kernel_launch(void* const* d_in, const int* in_sizes, int n_in,
                              void* d_out, int out_size, void* d_ws, size_t ws_size,
                              hipStream_t stream) {
    const float* inputs = (const float*)d_in[0];
    // d_in[1] = target_len (== 8, hardcoded as TLEN)
    const float* Wih_e = (const float*)d_in[2];
    const float* Whh_e = (const float*)d_in[3];
    const float* b_e   = (const float*)d_in[4];
    const float* Wih_d = (const float*)d_in[5];
    const float* Whh_d = (const float*)d_in[6];
    const float* b_d   = (const float*)d_in[7];
    const float* We    = (const float*)d_in[8];
    const float* Wd    = (const float*)d_in[9];
    const float* Wv    = (const float*)d_in[10];
    const float* Wf    = (const float*)d_in[11];
    const float* bfp   = (const float*)d_in[12];
    float* out = (float*)d_out;

    const int B = in_sizes[0] / SEQ;  // 512

    seq2seq_kernel<<<dim3(B / 2), dim3(512), 0, stream>>>(
        inputs, Wih_e, Whh_e, b_e, Wih_d, Whh_d, b_d, We, Wd, Wv, Wf, bfp, out, B);
}

// Round 3
// 1040.663 us; speedup vs baseline: 2.0546x; 1.4593x over previous
//
#include <hip/hip_runtime.h>

#define HDIM 128
#define SEQ  14
#define G4   512   // 4*H
#define TLEN 8

typedef _Float16 h2 __attribute__((ext_vector_type(2)));

#if defined(__has_builtin)
#if __has_builtin(__builtin_amdgcn_fdot2)
#define HAVE_FDOT2 1
#endif
#endif

__device__ __forceinline__ float fdot2_(h2 a, h2 b, float c) {
#ifdef HAVE_FDOT2
    return __builtin_amdgcn_fdot2(a, b, c, false);
#else
    return c + (float)a.x * (float)b.x + (float)a.y * (float)b.y;
#endif
}

__device__ __forceinline__ h2 bc_h2(float f) { return __builtin_bit_cast(h2, f); }

__device__ __forceinline__ float frcp_(float x) { return __builtin_amdgcn_rcpf(x); }
__device__ __forceinline__ float fsig_(float x) { return frcp_(1.0f + __expf(-x)); }
__device__ __forceinline__ float ftanh_(float x) {
    // tanh(x) = 1 - 2/(e^{2x}+1); saturates correctly for |x| large.
    return 1.0f - 2.0f * frcp_(__expf(2.0f * x) + 1.0f);
}

// One block per 2 batch elements. 512 threads: thread j owns gate-column j of
// the recurrent weight matrix, stored as 64 packed-f16 pairs (shared by both
// elements). h is kept both fp32 (attention/output paths) and packed-f16 (gate
// mat-vec via v_dot2_f32_f16) in LDS.
__global__ __launch_bounds__(512, 2) void seq2seq_kernel(
    const float* __restrict__ inputs,   // [B, 14, 1]
    const float* __restrict__ Wih_e,    // [1, 512]
    const float* __restrict__ Whh_e,    // [128, 512]
    const float* __restrict__ b_e,      // [512]
    const float* __restrict__ Wih_d,
    const float* __restrict__ Whh_d,
    const float* __restrict__ b_d,
    const float* __restrict__ We,       // [128, 128]
    const float* __restrict__ Wd,       // [128, 128]
    const float* __restrict__ Wv,       // [128, 1]
    const float* __restrict__ Wf,       // [128, 1]
    const float* __restrict__ bfp,      // [1]
    float* __restrict__ out,            // [B*8] outputs then [B*14] total_attn
    int B)
{
    const int tid = threadIdx.x;
    const int b0  = blockIdx.x * 2;      // first of the two batch elements

    __shared__ __align__(16) _Float16 sh_hh[2][HDIM];   // packed h (gate input)
    __shared__ __align__(16) float sh_h[2][HDIM];       // fp32 h (attn/output)
    __shared__ __align__(16) float sh_g[2][G4];
    __shared__ __align__(16) float sh_enc[2][SEQ][HDIM];
    __shared__ __align__(16) float sh_encWe[2][SEQ][HDIM];
    __shared__ __align__(16) float sh_hWd[2][HDIM];
    __shared__ __align__(16) float sh_part[2][2][HDIM];
    __shared__ __align__(16) float sh_ctx[2][HDIM];
    __shared__ float sh_attn[2][SEQ];
    __shared__ float sh_attnsum[2][SEQ];
    __shared__ float sh_score[2][SEQ];
    __shared__ float sh_x[2];

    h2 w2[HDIM / 2];  // recurrent weight column `tid`, packed f16 pairs

    // ---------------- Phase 1: encoder ----------------
    #pragma unroll
    for (int k2 = 0; k2 < HDIM / 2; ++k2) {
        h2 p;
        p.x = (_Float16)Whh_e[(2 * k2) * G4 + tid];
        p.y = (_Float16)Whh_e[(2 * k2 + 1) * G4 + tid];
        w2[k2] = p;
    }
    float wih = Wih_e[tid];
    float bb  = b_e[tid];

    if (tid < 2 * HDIM) {
        sh_h[tid >> 7][tid & 127]  = 0.0f;
        sh_hh[tid >> 7][tid & 127] = (_Float16)0.0f;
    }
    if (tid < 2 * SEQ)  sh_attnsum[tid / SEQ][tid % SEQ] = 0.0f;
    float c = 0.0f;  // cell state for (e = tid>>7, j = tid&127), valid tid < 256
    __syncthreads();

    const float* inp0 = inputs + b0 * SEQ;
    const float* inp1 = inputs + (b0 + 1) * SEQ;

    const float4* H0 = (const float4*)(&sh_hh[0][0]);  // 16 float4 = 64 half2
    const float4* H1 = (const float4*)(&sh_hh[1][0]);

    for (int t = 0; t < SEQ; ++t) {
        float a0 = fmaf(inp0[t], wih, bb), a0b = 0.0f;
        float a1 = fmaf(inp1[t], wih, bb), a1b = 0.0f;
        #pragma unroll
        for (int i = 0; i < 16; ++i) {
            float4 u = H0[i];
            float4 v = H1[i];
            int k = i * 4;
            a0  = fdot2_(bc_h2(u.x), w2[k],     a0);
            a0b = fdot2_(bc_h2(u.y), w2[k + 1], a0b);
            a0  = fdot2_(bc_h2(u.z), w2[k + 2], a0);
            a0b = fdot2_(bc_h2(u.w), w2[k + 3], a0b);
            a1  = fdot2_(bc_h2(v.x), w2[k],     a1);
            a1b = fdot2_(bc_h2(v.y), w2[k + 1], a1b);
            a1  = fdot2_(bc_h2(v.z), w2[k + 2], a1);
            a1b = fdot2_(bc_h2(v.w), w2[k + 3], a1b);
        }
        sh_g[0][tid] = a0 + a0b;
        sh_g[1][tid] = a1 + a1b;
        __syncthreads();
        if (tid < 256) {
            int e = tid >> 7, j = tid & 127;
            float ig = fsig_(sh_g[e][j]);
            float fg = fsig_(sh_g[e][j + HDIM]);
            float gg = ftanh_(sh_g[e][j + 2 * HDIM]);
            float og = fsig_(sh_g[e][j + 3 * HDIM]);
            c = fmaf(fg, c, ig * gg);
            float hn = og * ftanh_(c);
            sh_h[e][j]  = hn;
            sh_hh[e][j] = (_Float16)hn;
            sh_enc[e][t][j] = hn;
        }
        __syncthreads();
    }

    // Precompute enc_out @ We once (reused by all 8 decoder steps).
    for (int idx = tid; idx < 2 * SEQ * HDIM; idx += 512) {
        int e = idx / (SEQ * HDIM), r = idx % (SEQ * HDIM);
        int t = r >> 7, j = r & 127;
        float a = 0.0f;
        for (int k = 0; k < HDIM; ++k)
            a = fmaf(sh_enc[e][t][k], We[k * HDIM + j], a);
        sh_encWe[e][t][j] = a;
    }

    // ---------------- Phase 2: decoder ----------------
    #pragma unroll
    for (int k2 = 0; k2 < HDIM / 2; ++k2) {
        h2 p;
        p.x = (_Float16)Whh_d[(2 * k2) * G4 + tid];
        p.y = (_Float16)Whh_d[(2 * k2 + 1) * G4 + tid];
        w2[k2] = p;
    }
    wih = Wih_d[tid];
    bb  = b_d[tid];

    if (tid < 2) sh_x[tid] = inputs[(b0 + tid) * SEQ + (SEQ - 1)];
    __syncthreads();  // encWe + x visible

    for (int d = 0; d < TLEN; ++d) {
        // --- attention: hWd[e][j] = sum_k h[e][k] * Wd[k][j], 2-way k-split ---
        {
            int e = tid >> 8, p = (tid >> 7) & 1, j = tid & 127;
            float a = 0.0f;
            const float* wd = Wd + (p * 64) * HDIM + j;
            #pragma unroll
            for (int k = 0; k < 64; ++k)
                a = fmaf(sh_h[e][p * 64 + k], wd[k * HDIM], a);
            sh_part[e][p][j] = a;
        }
        __syncthreads();
        if (tid < 256) {
            int e = tid >> 7, j = tid & 127;
            sh_hWd[e][j] = sh_part[e][0][j] + sh_part[e][1][j];
        }
        __syncthreads();

        // --- scores: e[t] = sum_j tanh(encWe[t][j] + hWd[j]) * Wv[j] ---
        if (tid < 2 * SEQ * 16) {
            int e = tid / (SEQ * 16), r = tid % (SEQ * 16);
            int t = r >> 4, l = r & 15;
            float s = 0.0f;
            #pragma unroll
            for (int j0 = 0; j0 < HDIM; j0 += 16)
                s = fmaf(ftanh_(sh_encWe[e][t][j0 + l] + sh_hWd[e][j0 + l]), Wv[j0 + l], s);
            s += __shfl_down(s, 8, 16);
            s += __shfl_down(s, 4, 16);
            s += __shfl_down(s, 2, 16);
            s += __shfl_down(s, 1, 16);
            if (l == 0) sh_score[e][t] = s;
        }
        __syncthreads();

        // --- softmax over 14 (serial per element; e0 on wave0, e1 on wave1) ---
        if ((tid & 63) == 0 && tid < 128) {
            int e = tid >> 6;
            float m = sh_score[e][0];
            for (int t = 1; t < SEQ; ++t) m = fmaxf(m, sh_score[e][t]);
            float ssum = 0.0f;
            for (int t = 0; t < SEQ; ++t) {
                float ev = __expf(sh_score[e][t] - m);
                sh_attn[e][t] = ev;
                ssum += ev;
            }
            float inv = frcp_(ssum);
            for (int t = 0; t < SEQ; ++t) {
                float a = sh_attn[e][t] * inv;
                sh_attn[e][t] = a;
                sh_attnsum[e][t] += a;
            }
        }
        __syncthreads();

        // --- context[e][k] = sum_t attn[e][t] * enc_out[e][t][k] ---
        if (tid < 256) {
            int e = tid >> 7, j = tid & 127;
            float a = 0.0f;
            #pragma unroll
            for (int t = 0; t < SEQ; ++t)
                a = fmaf(sh_attn[e][t], sh_enc[e][t][j], a);
            sh_ctx[e][j] = a;
        }
        __syncthreads();

        // --- decoder LSTM: 129 scalar-input steps ---
        for (int s = 0; s < HDIM + 1; ++s) {
            float x0 = (s < HDIM) ? sh_ctx[0][s] : sh_x[0];
            float x1 = (s < HDIM) ? sh_ctx[1][s] : sh_x[1];
            float a0 = fmaf(x0, wih, bb), a0b = 0.0f;
            float a1 = fmaf(x1, wih, bb), a1b = 0.0f;
            #pragma unroll
            for (int i = 0; i < 16; ++i) {
                float4 u = H0[i];
                float4 v = H1[i];
                int k = i * 4;
                a0  = fdot2_(bc_h2(u.x), w2[k],     a0);
                a0b = fdot2_(bc_h2(u.y), w2[k + 1], a0b);
                a0  = fdot2_(bc_h2(u.z), w2[k + 2], a0);
                a0b = fdot2_(bc_h2(u.w), w2[k + 3], a0b);
                a1  = fdot2_(bc_h2(v.x), w2[k],     a1);
                a1b = fdot2_(bc_h2(v.y), w2[k + 1], a1b);
                a1  = fdot2_(bc_h2(v.z), w2[k + 2], a1);
                a1b = fdot2_(bc_h2(v.w), w2[k + 3], a1b);
            }
            sh_g[0][tid] = a0 + a0b;
            sh_g[1][tid] = a1 + a1b;
            __syncthreads();
            if (tid < 256) {
                int e = tid >> 7, j = tid & 127;
                float ig = fsig_(sh_g[e][j]);
                float fg = fsig_(sh_g[e][j + HDIM]);
                float gg = ftanh_(sh_g[e][j + 2 * HDIM]);
                float og = fsig_(sh_g[e][j + 3 * HDIM]);
                c = fmaf(fg, c, ig * gg);
                float hn = og * ftanh_(c);
                sh_h[e][j]  = hn;
                sh_hh[e][j] = (_Float16)hn;
            }
            __syncthreads();
        }

        // --- out = h @ Wf + bf (scalar per elem); also becomes next x ---
        if (tid < 128) {
            int e = tid >> 6, l = tid & 63;
            float s = sh_h[e][l] * Wf[l] + sh_h[e][l + 64] * Wf[l + 64];
            s += __shfl_down(s, 32);
            s += __shfl_down(s, 16);
            s += __shfl_down(s, 8);
            s += __shfl_down(s, 4);
            s += __shfl_down(s, 2);
            s += __shfl_down(s, 1);
            if (l == 0) {
                float o = s + bfp[0];
                out[(b0 + e) * TLEN + d] = o;
                sh_x[e] = o;
            }
        }
        __syncthreads();
    }

    // total_attn [B, 14, 1]
    if (tid < 2 * SEQ) {
        int e = tid / SEQ, t = tid % SEQ;
        out[B * TLEN + (b0 + e) * SEQ + t] = sh_attnsum[e][t];
    }
}

extern "C" void kernel_launch(void* const* d_in, const int* in_sizes, int n_in,
                              void* d_out, int out_size, void* d_ws, size_t ws_size,
                              hipStream_t stream) {
    const float* inputs = (const float*)d_in[0];
    // d_in[1] = target_len (== 8, hardcoded as TLEN)
    const float* Wih_e = (const float*)d_in[2];
    const float* Whh_e = (const float*)d_in[3];
    const float* b_e   = (const float*)d_in[4];
    const float* Wih_d = (const float*)d_in[5];
    const float* Whh_d = (const float*)d_in[6];
    const float* b_d   = (const float*)d_in[7];
    const float* We    = (const float*)d_in[8];
    const float* Wd    = (const float*)d_in[9];
    const float* Wv    = (const float*)d_in[10];
    const float* Wf    = (const float*)d_in[11];
    const float* bfp   = (const float*)d_in[12];
    float* out = (float*)d_out;

    const int B = in_sizes[0] / SEQ;  // 512

    seq2seq_kernel<<<dim3(B / 2), dim3(512), 0, stream>>>(
        inputs, Wih_e, Whh_e, b_e, Wih_d, Whh_d, b_d, We, Wd, Wv, Wf, bfp, out, B);
}

// Round 4
// 963.543 us; speedup vs baseline: 2.2191x; 1.0800x over previous
//
#include <hip/hip_runtime.h>

#define HDIM 128
#define SEQ  14
#define G4   512
#define TLEN 8
#define EPB  16     // batch elements per block
#define NTHR 512
#define HPAD 136    // padded h row length in halves (272 B, bank-spread)

typedef _Float16 half8 __attribute__((ext_vector_type(8)));
typedef _Float16 half4 __attribute__((ext_vector_type(4)));
typedef float f32x4 __attribute__((ext_vector_type(4)));

struct __align__(16) SMem {
    _Float16 hbuf[2][EPB][HPAD];       // double-buffered h (f16, MFMA-A layout)
    _Float16 ench[SEQ][EPB][HDIM];     // encoder outputs, f16
    _Float16 encWe[SEQ][EPB][HDIM];    // enc_out @ We, f16
    _Float16 hWdh[EPB][HDIM];          // h @ Wd, f16
    float ctxT[HDIM + 1][EPB];         // context transposed; row 128 = x
    float inpT[SEQ][EPB];              // inputs transposed
    float attnw[EPB][SEQ];
    float asum[EPB][SEQ];
    float scoreP[2][EPB][SEQ];
    float wv[HDIM];
    float wf[HDIM];
};  // 141,248 B

extern __shared__ char smem_raw[];

__device__ __forceinline__ float frcp_(float x) { return __builtin_amdgcn_rcpf(x); }
__device__ __forceinline__ float fsig_(float x) { return frcp_(1.0f + __expf(-x)); }
__device__ __forceinline__ float ftanh_(float x) {
    return 1.0f - 2.0f * frcp_(__expf(2.0f * x) + 1.0f);
}

__global__ __launch_bounds__(NTHR, 1) void seq2seq_kernel(
    const float* __restrict__ inputs,
    const float* __restrict__ Wih_e, const float* __restrict__ Whh_e, const float* __restrict__ b_e,
    const float* __restrict__ Wih_d, const float* __restrict__ Whh_d, const float* __restrict__ b_d,
    const float* __restrict__ We, const float* __restrict__ Wd,
    const float* __restrict__ Wv, const float* __restrict__ Wf, const float* __restrict__ bfp,
    float* __restrict__ out, int B)
{
    const int tid  = threadIdx.x;
    const int b0   = blockIdx.x * EPB;
    const int w    = tid >> 6;      // wave 0..7 -> h-cols [16w,16w+16)
    const int lane = tid & 63;
    const int q    = lane >> 4;     // quad
    const int l    = lane & 15;
    SMem& S = *reinterpret_cast<SMem*>(smem_raw);

    // ---- init LDS ----
    for (int i = tid; i < 2 * EPB * HPAD / 2; i += NTHR)
        ((unsigned int*)&S.hbuf[0][0][0])[i] = 0u;
    for (int i = tid; i < SEQ * EPB; i += NTHR) {
        int t = i / EPB, m = i % EPB;
        S.inpT[t][m] = inputs[(b0 + m) * SEQ + t];
    }
    for (int i = tid; i < EPB * SEQ; i += NTHR) ((float*)S.asum)[i] = 0.0f;
    if (tid < HDIM) { S.wv[tid] = Wv[tid]; S.wf[tid] = Wf[tid]; }
    if (tid < EPB)  S.ctxT[HDIM][tid] = inputs[(b0 + tid) * SEQ + (SEQ - 1)];

    // ---- encoder weight fragments (B-operand: B[k=32kt+8q+jj][n]) ----
    half8 whh[4][4];
    float wihg[4], bg[4];
    #pragma unroll
    for (int g = 0; g < 4; ++g) {
        int n = g * HDIM + 16 * w + l;
        wihg[g] = Wih_e[n];
        bg[g]   = b_e[n];
        #pragma unroll
        for (int kt = 0; kt < 4; ++kt) {
            half8 f;
            #pragma unroll
            for (int jj = 0; jj < 8; ++jj)
                f[jj] = (_Float16)Whh_e[(32 * kt + 8 * q + jj) * G4 + n];
            whh[g][kt] = f;
        }
    }
    f32x4 cc = {0.f, 0.f, 0.f, 0.f};   // cell state, rows m=4q+r
    __syncthreads();

    // ---- encoder: 14 MFMA LSTM steps ----
    int cur = 0;
    for (int t = 0; t < SEQ; ++t) {
        f32x4 xv = *(const f32x4*)&S.inpT[t][q * 4];
        f32x4 acc[4];
        #pragma unroll
        for (int g = 0; g < 4; ++g) {
            f32x4 a;
            #pragma unroll
            for (int r = 0; r < 4; ++r) a[r] = fmaf(xv[r], wihg[g], bg[g]);
            acc[g] = a;
        }
        const _Float16* hrow = &S.hbuf[cur][l][0];
        half8 af[4];
        #pragma unroll
        for (int kt = 0; kt < 4; ++kt) af[kt] = *(const half8*)&hrow[32 * kt + 8 * q];
        #pragma unroll
        for (int g = 0; g < 4; ++g)
            #pragma unroll
            for (int kt = 0; kt < 4; ++kt)
                acc[g] = __builtin_amdgcn_mfma_f32_16x16x32_f16(af[kt], whh[g][kt], acc[g], 0, 0, 0);
        int j = 16 * w + l;
        #pragma unroll
        for (int r = 0; r < 4; ++r) {
            float ig = fsig_(acc[0][r]);
            float fg = fsig_(acc[1][r]);
            float gg = ftanh_(acc[2][r]);
            float og = fsig_(acc[3][r]);
            cc[r] = fmaf(fg, cc[r], ig * gg);
            float hn = og * ftanh_(cc[r]);
            _Float16 hh = (_Float16)hn;
            S.hbuf[cur ^ 1][q * 4 + r][j] = hh;
            S.ench[t][q * 4 + r][j] = hh;
        }
        cur ^= 1;
        __syncthreads();
    }

    // ---- encWe = enc_out @ We (MFMA, one-time) ----
    {
        half8 wef[4];
        int n = 16 * w + l;
        #pragma unroll
        for (int kt = 0; kt < 4; ++kt) {
            half8 f;
            #pragma unroll
            for (int jj = 0; jj < 8; ++jj)
                f[jj] = (_Float16)We[(32 * kt + 8 * q + jj) * HDIM + n];
            wef[kt] = f;
        }
        for (int t = 0; t < SEQ; ++t) {
            const _Float16* er = &S.ench[t][l][0];
            f32x4 dv = {0.f, 0.f, 0.f, 0.f};
            #pragma unroll
            for (int kt = 0; kt < 4; ++kt) {
                half8 a = *(const half8*)&er[32 * kt + 8 * q];
                dv = __builtin_amdgcn_mfma_f32_16x16x32_f16(a, wef[kt], dv, 0, 0, 0);
            }
            #pragma unroll
            for (int r = 0; r < 4; ++r)
                S.encWe[t][q * 4 + r][n] = (_Float16)dv[r];
        }
    }

    // ---- decoder weights (overwrite regs) ----
    half8 wdf[4];
    #pragma unroll
    for (int g = 0; g < 4; ++g) {
        int n = g * HDIM + 16 * w + l;
        wihg[g] = Wih_d[n];
        bg[g]   = b_d[n];
        #pragma unroll
        for (int kt = 0; kt < 4; ++kt) {
            half8 f;
            #pragma unroll
            for (int jj = 0; jj < 8; ++jj)
                f[jj] = (_Float16)Whh_d[(32 * kt + 8 * q + jj) * G4 + n];
            whh[g][kt] = f;
        }
    }
    {
        int n = 16 * w + l;
        #pragma unroll
        for (int kt = 0; kt < 4; ++kt) {
            half8 f;
            #pragma unroll
            for (int jj = 0; jj < 8; ++jj)
                f[jj] = (_Float16)Wd[(32 * kt + 8 * q + jj) * HDIM + n];
            wdf[kt] = f;
        }
    }
    float bf0 = bfp[0];
    __syncthreads();   // encWe visible

    // ---- decoder: 8 steps ----
    for (int d = 0; d < TLEN; ++d) {
        // hWd = h @ Wd (MFMA)
        {
            const _Float16* hrow = &S.hbuf[cur][l][0];
            f32x4 dv = {0.f, 0.f, 0.f, 0.f};
            #pragma unroll
            for (int kt = 0; kt < 4; ++kt) {
                half8 a = *(const half8*)&hrow[32 * kt + 8 * q];
                dv = __builtin_amdgcn_mfma_f32_16x16x32_f16(a, wdf[kt], dv, 0, 0, 0);
            }
            int n = 16 * w + l;
            #pragma unroll
            for (int r = 0; r < 4; ++r)
                S.hWdh[q * 4 + r][n] = (_Float16)dv[r];
        }
        __syncthreads();
        // scores (448 threads: (m,t) x 2 j-halves)
        if (tid < 2 * EPB * SEQ) {
            int p = tid >> 1, hf = tid & 1;
            int m = p & 15, t = p >> 4;
            const _Float16* ew  = &S.encWe[t][m][hf * 64];
            const _Float16* hw  = &S.hWdh[m][hf * 64];
            const float*    wvp = &S.wv[hf * 64];
            float s = 0.f;
            for (int j0 = 0; j0 < 64; j0 += 8) {
                half8 ev = *(const half8*)&ew[j0];
                half8 hv = *(const half8*)&hw[j0];
                #pragma unroll
                for (int i = 0; i < 8; ++i)
                    s = fmaf(ftanh_((float)ev[i] + (float)hv[i]), wvp[j0 + i], s);
            }
            S.scoreP[hf][m][t] = s;
        }
        __syncthreads();
        // softmax over 14, per batch row
        if (tid < EPB) {
            int m = tid;
            float sc[SEQ]; float mx = -1e30f;
            #pragma unroll
            for (int t = 0; t < SEQ; ++t) {
                sc[t] = S.scoreP[0][m][t] + S.scoreP[1][m][t];
                mx = fmaxf(mx, sc[t]);
            }
            float ssum = 0.f;
            #pragma unroll
            for (int t = 0; t < SEQ; ++t) { float e = __expf(sc[t] - mx); sc[t] = e; ssum += e; }
            float inv = frcp_(ssum);
            #pragma unroll
            for (int t = 0; t < SEQ; ++t) {
                float a = sc[t] * inv;
                S.attnw[m][t] = a;
                S.asum[m][t] += a;
            }
        }
        __syncthreads();
        // context -> ctxT rows 0..127
        {
            int m = tid >> 5, kg = tid & 31;
            float a0 = 0, a1 = 0, a2 = 0, a3 = 0;
            #pragma unroll
            for (int t = 0; t < SEQ; ++t) {
                float at = S.attnw[m][t];
                half4 hv = *(const half4*)&S.ench[t][m][kg * 4];
                a0 = fmaf(at, (float)hv[0], a0);
                a1 = fmaf(at, (float)hv[1], a1);
                a2 = fmaf(at, (float)hv[2], a2);
                a3 = fmaf(at, (float)hv[3], a3);
            }
            S.ctxT[kg * 4 + 0][m] = a0;
            S.ctxT[kg * 4 + 1][m] = a1;
            S.ctxT[kg * 4 + 2][m] = a2;
            S.ctxT[kg * 4 + 3][m] = a3;
        }
        __syncthreads();
        // decoder LSTM: 129 steps (row 128 of ctxT = x)
        for (int s = 0; s <= HDIM; ++s) {
            f32x4 xv = *(const f32x4*)&S.ctxT[s][q * 4];
            f32x4 acc[4];
            #pragma unroll
            for (int g = 0; g < 4; ++g) {
                f32x4 a;
                #pragma unroll
                for (int r = 0; r < 4; ++r) a[r] = fmaf(xv[r], wihg[g], bg[g]);
                acc[g] = a;
            }
            const _Float16* hrow = &S.hbuf[cur][l][0];
            half8 af[4];
            #pragma unroll
            for (int kt = 0; kt < 4; ++kt) af[kt] = *(const half8*)&hrow[32 * kt + 8 * q];
            #pragma unroll
            for (int g = 0; g < 4; ++g)
                #pragma unroll
                for (int kt = 0; kt < 4; ++kt)
                    acc[g] = __builtin_amdgcn_mfma_f32_16x16x32_f16(af[kt], whh[g][kt], acc[g], 0, 0, 0);
            int j = 16 * w + l;
            #pragma unroll
            for (int r = 0; r < 4; ++r) {
                float ig = fsig_(acc[0][r]);
                float fg = fsig_(acc[1][r]);
                float gg = ftanh_(acc[2][r]);
                float og = fsig_(acc[3][r]);
                cc[r] = fmaf(fg, cc[r], ig * gg);
                float hn = og * ftanh_(cc[r]);
                S.hbuf[cur ^ 1][q * 4 + r][j] = (_Float16)hn;
            }
            cur ^= 1;
            __syncthreads();
        }
        // output projection; result is next x
        if (tid < 256) {
            int m = tid >> 4, part = tid & 15;
            half8 hv = *(const half8*)&S.hbuf[cur][m][part * 8];
            float sacc = 0.f;
            #pragma unroll
            for (int i = 0; i < 8; ++i) sacc = fmaf((float)hv[i], S.wf[part * 8 + i], sacc);
            sacc += __shfl_down(sacc, 8, 16);
            sacc += __shfl_down(sacc, 4, 16);
            sacc += __shfl_down(sacc, 2, 16);
            sacc += __shfl_down(sacc, 1, 16);
            if (part == 0) {
                float o = sacc + bf0;
                out[(b0 + m) * TLEN + d] = o;
                S.ctxT[HDIM][m] = o;
            }
        }
        __syncthreads();
    }

    // total_attn [B, 14, 1]
    for (int i = tid; i < EPB * SEQ; i += NTHR) {
        int m = i / SEQ, t = i % SEQ;
        out[B * TLEN + (b0 + m) * SEQ + t] = S.asum[m][t];
    }
}

extern "C" void kernel_launch(void* const* d_in, const int* in_sizes, int n_in,
                              void* d_out, int out_size, void* d_ws, size_t ws_size,
                              hipStream_t stream) {
    const float* inputs = (const float*)d_in[0];
    const float* Wih_e = (const float*)d_in[2];
    const float* Whh_e = (const float*)d_in[3];
    const float* b_e   = (const float*)d_in[4];
    const float* Wih_d = (const float*)d_in[5];
    const float* Whh_d = (const float*)d_in[6];
    const float* b_d   = (const float*)d_in[7];
    const float* We    = (const float*)d_in[8];
    const float* Wd    = (const float*)d_in[9];
    const float* Wv    = (const float*)d_in[10];
    const float* Wf    = (const float*)d_in[11];
    const float* bfp   = (const float*)d_in[12];
    float* out = (float*)d_out;

    const int B = in_sizes[0] / SEQ;  // 512
    const int smem_bytes = (int)sizeof(SMem);

    (void)hipFuncSetAttribute((const void*)seq2seq_kernel,
                              hipFuncAttributeMaxDynamicSharedMemorySize, smem_bytes);

    seq2seq_kernel<<<dim3(B / EPB), dim3(NTHR), smem_bytes, stream>>>(
        inputs, Wih_e, Whh_e, b_e, Wih_d, Whh_d, b_d, We, Wd, Wv, Wf, bfp, out, B);
}

// Round 5
// 754.060 us; speedup vs baseline: 2.8356x; 1.2778x over previous
//
#include <hip/hip_runtime.h>

#define HDIM 128
#define SEQ  14
#define G4   512
#define TLEN 8
#define EPB  2      // batch elements per block -> 256 blocks, all CUs
#define NTHR 512
#define HROW 136    // hbuf row pitch in halves (272 B = 68 words; A-read at b128 floor)

typedef _Float16 half8 __attribute__((ext_vector_type(8)));
typedef float f32x4 __attribute__((ext_vector_type(4)));

__device__ __forceinline__ float frcp_(float x) { return __builtin_amdgcn_rcpf(x); }
__device__ __forceinline__ float fsig_(float x) { return frcp_(1.0f + __expf(-x)); }
__device__ __forceinline__ float ftanh_(float x) {
    return 1.0f - 2.0f * frcp_(__expf(2.0f * x) + 1.0f);
}

struct __align__(16) SMem {
    _Float16 hbuf[2][16][HROW];        // h in MFMA-A row layout; only rows 0,1 written
    _Float16 ench[SEQ][EPB][HDIM];     // encoder outputs (f16)
    _Float16 encWe[SEQ][EPB][HDIM];    // enc_out @ We (f16)
    _Float16 hWdh[EPB][HDIM];          // h @ Wd (f16)
    float gPK[EPB][HDIM][4];           // gates, interleaved i,f,g,o per (e,j)
    float ctxT[HDIM + 1][17];          // ctx dim-major, width 17 (bank spread); row 128 = x
    float inpT[SEQ][16];               // encoder inputs, 16-wide (rows 2..15 zero)
    float attnw[EPB][SEQ];
    float asum[EPB][SEQ];
    float score[EPB][SEQ];
    float wv[HDIM];
    float wf[HDIM];
};  // ~38.7 KB

__global__ __launch_bounds__(NTHR, 2) void seq2seq_kernel(
    const float* __restrict__ inputs,
    const float* __restrict__ Wih_e, const float* __restrict__ Whh_e, const float* __restrict__ b_e,
    const float* __restrict__ Wih_d, const float* __restrict__ Whh_d, const float* __restrict__ b_d,
    const float* __restrict__ We, const float* __restrict__ Wd,
    const float* __restrict__ Wv, const float* __restrict__ Wf, const float* __restrict__ bfp,
    float* __restrict__ out, int B)
{
    const int tid  = threadIdx.x;
    const int b0   = blockIdx.x * EPB;
    const int w    = tid >> 6;       // wave 0..7: gate-cols [16w,16w+16) of each gate
    const int lane = tid & 63;
    const int q    = lane >> 4;      // quad
    const int l    = lane & 15;
    __shared__ SMem S;

    // ---- init ----
    if (tid < 2 * HDIM) {            // zero valid h rows of both buffers
        int e = tid >> 7, j = tid & 127;
        S.hbuf[0][e][j] = (_Float16)0.0f;
        S.hbuf[1][e][j] = (_Float16)0.0f;
    }
    if (tid < SEQ * 16) {
        int t = tid >> 4, m = tid & 15;
        S.inpT[t][m] = (m < EPB) ? inputs[(b0 + m) * SEQ + t] : 0.0f;
    }
    if (tid < EPB * SEQ) { int e = tid / SEQ, t = tid % SEQ; S.asum[e][t] = 0.0f; }
    if (tid < HDIM) { S.wv[tid] = Wv[tid]; S.wf[tid] = Wf[tid]; }
    if (tid < EPB)  S.ctxT[HDIM][tid] = inputs[(b0 + tid) * SEQ + (SEQ - 1)];

    // ---- encoder recurrent weights (B-frag: B[k=8q+j (+32kt)][n=16w+l], gate g) ----
    half8 whh[4][4];
    float wihg[4], bg[4];
    #pragma unroll
    for (int g = 0; g < 4; ++g) {
        int n = g * HDIM + 16 * w + l;
        wihg[g] = Wih_e[n];
        bg[g]   = b_e[n];
        #pragma unroll
        for (int kt = 0; kt < 4; ++kt) {
            half8 f;
            #pragma unroll
            for (int jj = 0; jj < 8; ++jj)
                f[jj] = (_Float16)Whh_e[(32 * kt + 8 * q + jj) * G4 + n];
            whh[g][kt] = f;
        }
    }
    float c = 0.0f;   // cell state owned by activation thread (tid<256 -> (e,j))
    __syncthreads();

    int cur = 0;
    // ---- encoder: 14 steps ----
    for (int t = 0; t < SEQ; ++t) {
        f32x4 acc[4];
        #pragma unroll
        for (int g = 0; g < 4; ++g)
            #pragma unroll
            for (int r = 0; r < 4; ++r)
                acc[g][r] = fmaf(S.inpT[t][4 * q + r], wihg[g], bg[g]);
        const _Float16* hr = &S.hbuf[cur][l][0];
        half8 af[4];
        #pragma unroll
        for (int kt = 0; kt < 4; ++kt) af[kt] = *(const half8*)&hr[32 * kt + 8 * q];
        #pragma unroll
        for (int g = 0; g < 4; ++g)
            #pragma unroll
            for (int kt = 0; kt < 4; ++kt)
                acc[g] = __builtin_amdgcn_mfma_f32_16x16x32_f16(af[kt], whh[g][kt], acc[g], 0, 0, 0);
        if (q == 0) {                 // D rows 0,1 = elements 0,1
            int j = 16 * w + l;
            f32x4 g0 = {acc[0][0], acc[1][0], acc[2][0], acc[3][0]};
            f32x4 g1 = {acc[0][1], acc[1][1], acc[2][1], acc[3][1]};
            *(f32x4*)&S.gPK[0][j][0] = g0;
            *(f32x4*)&S.gPK[1][j][0] = g1;
        }
        __syncthreads();
        if (tid < 256) {
            int e = tid >> 7, j = tid & 127;
            f32x4 gv = *(const f32x4*)&S.gPK[e][j][0];
            float ig = fsig_(gv[0]);
            float fg = fsig_(gv[1]);
            float gg = ftanh_(gv[2]);
            float og = fsig_(gv[3]);
            c = fmaf(fg, c, ig * gg);
            float hn = og * ftanh_(c);
            _Float16 hh = (_Float16)hn;
            S.hbuf[cur ^ 1][e][j] = hh;
            S.ench[t][e][j] = hh;
        }
        cur ^= 1;
        __syncthreads();
    }

    // ---- encWe = enc_out @ We (one-time; A-rows>=2 garbage, quarantined) ----
    {
        half8 wef[4];
        int n = 16 * w + l;
        #pragma unroll
        for (int kt = 0; kt < 4; ++kt) {
            half8 f;
            #pragma unroll
            for (int jj = 0; jj < 8; ++jj)
                f[jj] = (_Float16)We[(32 * kt + 8 * q + jj) * HDIM + n];
            wef[kt] = f;
        }
        for (int t = 0; t < SEQ; ++t) {
            const _Float16* er = &S.ench[t][l][0];   // rows l>=2 read neighboring LDS (defined, unused)
            f32x4 dv = {0.f, 0.f, 0.f, 0.f};
            #pragma unroll
            for (int kt = 0; kt < 4; ++kt) {
                half8 a = *(const half8*)&er[32 * kt + 8 * q];
                dv = __builtin_amdgcn_mfma_f32_16x16x32_f16(a, wef[kt], dv, 0, 0, 0);
            }
            if (q == 0) {
                S.encWe[t][0][n] = (_Float16)dv[0];
                S.encWe[t][1][n] = (_Float16)dv[1];
            }
        }
    }

    // ---- decoder weights ----
    half8 wdf[4];
    #pragma unroll
    for (int g = 0; g < 4; ++g) {
        int n = g * HDIM + 16 * w + l;
        wihg[g] = Wih_d[n];
        bg[g]   = b_d[n];
        #pragma unroll
        for (int kt = 0; kt < 4; ++kt) {
            half8 f;
            #pragma unroll
            for (int jj = 0; jj < 8; ++jj)
                f[jj] = (_Float16)Whh_d[(32 * kt + 8 * q + jj) * G4 + n];
            whh[g][kt] = f;
        }
    }
    {
        int n = 16 * w + l;
        #pragma unroll
        for (int kt = 0; kt < 4; ++kt) {
            half8 f;
            #pragma unroll
            for (int jj = 0; jj < 8; ++jj)
                f[jj] = (_Float16)Wd[(32 * kt + 8 * q + jj) * HDIM + n];
            wdf[kt] = f;
        }
    }
    float bf0 = bfp[0];
    __syncthreads();   // encWe visible

    // ---- decoder: 8 steps ----
    for (int d = 0; d < TLEN; ++d) {
        // hWd = h @ Wd (wave w -> cols [16w,16w+16))
        {
            const _Float16* hr = &S.hbuf[cur][l][0];
            f32x4 dv = {0.f, 0.f, 0.f, 0.f};
            #pragma unroll
            for (int kt = 0; kt < 4; ++kt) {
                half8 a = *(const half8*)&hr[32 * kt + 8 * q];
                dv = __builtin_amdgcn_mfma_f32_16x16x32_f16(a, wdf[kt], dv, 0, 0, 0);
            }
            if (q == 0) {
                int n = 16 * w + l;
                S.hWdh[0][n] = (_Float16)dv[0];
                S.hWdh[1][n] = (_Float16)dv[1];
            }
        }
        __syncthreads();
        // scores: 448 threads = (m,t) x 16 lanes, 8 j's each
        if (tid < 2 * SEQ * 16) {
            int p = tid >> 4, sub = tid & 15;
            int m = p & 1, t = p >> 1;
            const _Float16* ew = &S.encWe[t][m][0];
            const _Float16* hw = &S.hWdh[m][0];
            float s = 0.0f;
            #pragma unroll
            for (int i = 0; i < 8; ++i) {
                int j = sub * 8 + i;
                s = fmaf(ftanh_((float)ew[j] + (float)hw[j]), S.wv[j], s);
            }
            s += __shfl_down(s, 8, 16);
            s += __shfl_down(s, 4, 16);
            s += __shfl_down(s, 2, 16);
            s += __shfl_down(s, 1, 16);
            if (sub == 0) S.score[m][t] = s;
        }
        __syncthreads();
        // softmax over 14 per element
        if (tid < EPB) {
            int m = tid;
            float sc[SEQ]; float mx = -1e30f;
            #pragma unroll
            for (int t = 0; t < SEQ; ++t) { sc[t] = S.score[m][t]; mx = fmaxf(mx, sc[t]); }
            float ssum = 0.0f;
            #pragma unroll
            for (int t = 0; t < SEQ; ++t) { float e = __expf(sc[t] - mx); sc[t] = e; ssum += e; }
            float inv = frcp_(ssum);
            #pragma unroll
            for (int t = 0; t < SEQ; ++t) {
                float a = sc[t] * inv;
                S.attnw[m][t] = a;
                S.asum[m][t] += a;
            }
        }
        __syncthreads();
        // context -> ctxT[j][e]
        if (tid < 256) {
            int e = tid >> 7, j = tid & 127;
            float a = 0.0f;
            #pragma unroll
            for (int t = 0; t < SEQ; ++t)
                a = fmaf(S.attnw[e][t], (float)S.ench[t][e][j], a);
            S.ctxT[j][e] = a;
        }
        __syncthreads();
        // decoder LSTM: 129 steps; x = ctxT[s][m], row 128 = prev output
        for (int s = 0; s <= HDIM; ++s) {
            f32x4 acc[4];
            float x0 = S.ctxT[s][4 * q + 0];
            float x1 = S.ctxT[s][4 * q + 1];
            float x2 = S.ctxT[s][4 * q + 2];
            float x3 = S.ctxT[s][4 * q + 3];
            #pragma unroll
            for (int g = 0; g < 4; ++g) {
                acc[g][0] = fmaf(x0, wihg[g], bg[g]);
                acc[g][1] = fmaf(x1, wihg[g], bg[g]);
                acc[g][2] = fmaf(x2, wihg[g], bg[g]);
                acc[g][3] = fmaf(x3, wihg[g], bg[g]);
            }
            const _Float16* hr = &S.hbuf[cur][l][0];
            half8 af[4];
            #pragma unroll
            for (int kt = 0; kt < 4; ++kt) af[kt] = *(const half8*)&hr[32 * kt + 8 * q];
            #pragma unroll
            for (int g = 0; g < 4; ++g)
                #pragma unroll
                for (int kt = 0; kt < 4; ++kt)
                    acc[g] = __builtin_amdgcn_mfma_f32_16x16x32_f16(af[kt], whh[g][kt], acc[g], 0, 0, 0);
            if (q == 0) {
                int j = 16 * w + l;
                f32x4 g0 = {acc[0][0], acc[1][0], acc[2][0], acc[3][0]};
                f32x4 g1 = {acc[0][1], acc[1][1], acc[2][1], acc[3][1]};
                *(f32x4*)&S.gPK[0][j][0] = g0;
                *(f32x4*)&S.gPK[1][j][0] = g1;
            }
            __syncthreads();
            if (tid < 256) {
                int e = tid >> 7, j = tid & 127;
                f32x4 gv = *(const f32x4*)&S.gPK[e][j][0];
                float ig = fsig_(gv[0]);
                float fg = fsig_(gv[1]);
                float gg = ftanh_(gv[2]);
                float og = fsig_(gv[3]);
                c = fmaf(fg, c, ig * gg);
                float hn = og * ftanh_(c);
                S.hbuf[cur ^ 1][e][j] = (_Float16)hn;
            }
            cur ^= 1;
            __syncthreads();
        }
        // output projection -> next x
        if (tid < 32) {
            int m = tid >> 4, part = tid & 15;
            half8 hv = *(const half8*)&S.hbuf[cur][m][part * 8];
            float s = 0.0f;
            #pragma unroll
            for (int i = 0; i < 8; ++i) s = fmaf((float)hv[i], S.wf[part * 8 + i], s);
            s += __shfl_down(s, 8, 16);
            s += __shfl_down(s, 4, 16);
            s += __shfl_down(s, 2, 16);
            s += __shfl_down(s, 1, 16);
            if (part == 0) {
                float o = s + bf0;
                out[(b0 + m) * TLEN + d] = o;
                S.ctxT[HDIM][m] = o;
            }
        }
        __syncthreads();
    }

    // total_attn [B, 14, 1]
    if (tid < EPB * SEQ) {
        int m = tid / SEQ, t = tid % SEQ;
        out[B * TLEN + (b0 + m) * SEQ + t] = S.asum[m][t];
    }
}

extern "C" void kernel_launch(void* const* d_in, const int* in_sizes, int n_in,
                              void* d_out, int out_size, void* d_ws, size_t ws_size,
                              hipStream_t stream) {
    const float* inputs = (const float*)d_in[0];
    const float* Wih_e = (const float*)d_in[2];
    const float* Whh_e = (const float*)d_in[3];
    const float* b_e   = (const float*)d_in[4];
    const float* Wih_d = (const float*)d_in[5];
    const float* Whh_d = (const float*)d_in[6];
    const float* b_d   = (const float*)d_in[7];
    const float* We    = (const float*)d_in[8];
    const float* Wd    = (const float*)d_in[9];
    const float* Wv    = (const float*)d_in[10];
    const float* Wf    = (const float*)d_in[11];
    const float* bfp   = (const float*)d_in[12];
    float* out = (float*)d_out;

    const int B = in_sizes[0] / SEQ;  // 512

    seq2seq_kernel<<<dim3(B / EPB), dim3(NTHR), 0, stream>>>(
        inputs, Wih_e, Whh_e, b_e, Wih_d, Whh_d, b_d, We, Wd, Wv, Wf, bfp, out, B);
}